// Round 2
// baseline (283.394 us; speedup 1.0000x reference)
//
#include <hip/hip_runtime.h>

// out[N,32] = segment_sum(edge_val[e] * weight[edge_col[e], :], edge_row[e]) + bias
// R2: build unordered CSR in d_ws (histogram -> per-block-scan segment alloc ->
// packed bucket fill), then atomic-free gather with one 128B store per row.
// Fallback to R1 atomic scatter if ws_size too small.

#define FEAT 32

// ---------------- fallback (R1 baseline, known-good) ----------------
__global__ __launch_bounds__(256) void gnn_init_out(
    const float* __restrict__ bias, float* __restrict__ out, int total) {
    int i = blockIdx.x * blockDim.x + threadIdx.x;
    if (i < total) out[i] = bias[i & (FEAT - 1)];
}

__global__ __launch_bounds__(256) void gnn_scatter(
    const int* __restrict__ edge_row, const int* __restrict__ edge_col,
    const float* __restrict__ edge_val, const float* __restrict__ weight,
    float* __restrict__ out, int num_edges) {
    long long t = (long long)blockIdx.x * blockDim.x + threadIdx.x;
    int e = (int)(t >> 5);
    int f = (int)(t & (FEAT - 1));
    if (e < num_edges) {
        int r = edge_row[e];
        int c = edge_col[e];
        float v = edge_val[e];
        atomicAdd(out + r * FEAT + f, v * weight[c * FEAT + f]);
    }
}

// ---------------- CSR-build pipeline ----------------
// ws layout (ints): [counts: N][cursor: N][gcur: 1][pad][start: N][pad][bucket: E x u64]

__global__ __launch_bounds__(256) void k_zero(int* __restrict__ p, int n) {
    int i = blockIdx.x * blockDim.x + threadIdx.x;
    if (i < n) p[i] = 0;
}

__global__ __launch_bounds__(256) void k_hist(
    const int* __restrict__ edge_row, int* __restrict__ counts, int num_edges) {
    int e = blockIdx.x * blockDim.x + threadIdx.x;
    if (e < num_edges) atomicAdd(counts + edge_row[e], 1);
}

// Assign each row a contiguous segment: block-level exclusive scan in LDS,
// one global atomic per block. Segment order across blocks is arbitrary.
__global__ __launch_bounds__(256) void k_alloc(
    const int* __restrict__ counts, int* __restrict__ start,
    int* __restrict__ gcur, int n) {
    __shared__ int sdata[256];
    __shared__ int sbase;
    int i = blockIdx.x * 256 + threadIdx.x;
    int v = (i < n) ? counts[i] : 0;
    sdata[threadIdx.x] = v;
    __syncthreads();
    #pragma unroll
    for (int off = 1; off < 256; off <<= 1) {
        int t = (threadIdx.x >= off) ? sdata[threadIdx.x - off] : 0;
        __syncthreads();
        sdata[threadIdx.x] += t;
        __syncthreads();
    }
    if (threadIdx.x == 255) sbase = atomicAdd(gcur, sdata[255]);
    __syncthreads();
    if (i < n) start[i] = sbase + (sdata[threadIdx.x] - v);
}

__global__ __launch_bounds__(256) void k_fill(
    const int* __restrict__ edge_row, const int* __restrict__ edge_col,
    const float* __restrict__ edge_val, const int* __restrict__ start,
    int* __restrict__ cursor, unsigned long long* __restrict__ bucket,
    int num_edges) {
    int e = blockIdx.x * blockDim.x + threadIdx.x;
    if (e < num_edges) {
        int r = edge_row[e];
        int pos = start[r] + atomicAdd(cursor + r, 1);
        unsigned long long rec =
            ((unsigned long long)__float_as_uint(edge_val[e]) << 32) |
            (unsigned int)edge_col[e];
        bucket[pos] = rec;
    }
}

// 32 lanes per row; lane f accumulates feature f; one coalesced 128B store/row.
__global__ __launch_bounds__(256) void k_gather(
    const unsigned long long* __restrict__ bucket,
    const int* __restrict__ start, const int* __restrict__ counts,
    const float* __restrict__ weight, const float* __restrict__ bias,
    float* __restrict__ out, int n) {
    int r = blockIdx.x * 8 + (threadIdx.x >> 5);
    int f = threadIdx.x & 31;
    if (r >= n) return;
    int s = start[r];
    int c = counts[r];
    float acc = 0.f;
    int i = 0;
    for (; i + 2 <= c; i += 2) {  // 2-wide for memory-level parallelism
        unsigned long long p0 = bucket[s + i];
        unsigned long long p1 = bucket[s + i + 1];
        int c0 = (int)(p0 & 0xffffffffu);
        int c1 = (int)(p1 & 0xffffffffu);
        float v0 = __uint_as_float((unsigned)(p0 >> 32));
        float v1 = __uint_as_float((unsigned)(p1 >> 32));
        float w0 = weight[c0 * FEAT + f];
        float w1 = weight[c1 * FEAT + f];
        acc += v0 * w0;
        acc += v1 * w1;
    }
    if (i < c) {
        unsigned long long p0 = bucket[s + i];
        int c0 = (int)(p0 & 0xffffffffu);
        float v0 = __uint_as_float((unsigned)(p0 >> 32));
        acc += v0 * weight[c0 * FEAT + f];
    }
    out[r * FEAT + f] = acc + bias[f];
}

extern "C" void kernel_launch(void* const* d_in, const int* in_sizes, int n_in,
                              void* d_out, int out_size, void* d_ws, size_t ws_size,
                              hipStream_t stream) {
    const int*   edge_row = (const int*)d_in[0];
    const int*   edge_col = (const int*)d_in[1];
    const float* edge_val = (const float*)d_in[2];
    const float* weight   = (const float*)d_in[3];
    const float* bias     = (const float*)d_in[4];
    float* out = (float*)d_out;

    const int E = in_sizes[0];
    const int N = out_size / FEAT;

    // ws layout
    size_t counts_off = 0;                       // N ints
    size_t cursor_off = (size_t)N;               // N ints
    size_t gcur_off   = (size_t)2 * N;           // 1 int
    size_t start_off  = (size_t)2 * N + 2;       // N ints (even-aligned)
    size_t bucket_off_b = ((start_off + N) * 4 + 15) & ~(size_t)15;
    size_t need = bucket_off_b + (size_t)E * 8;

    if (ws_size < need) {  // fallback: R1 atomic scatter
        gnn_init_out<<<(out_size + 255) / 256, 256, 0, stream>>>(bias, out, out_size);
        long long threads = (long long)E * FEAT;
        gnn_scatter<<<(int)((threads + 255) / 256), 256, 0, stream>>>(
            edge_row, edge_col, edge_val, weight, out, E);
        return;
    }

    int* wsi = (int*)d_ws;
    int* counts = wsi + counts_off;
    int* cursor = wsi + cursor_off;
    int* gcur   = wsi + gcur_off;
    int* start  = wsi + start_off;
    unsigned long long* bucket = (unsigned long long*)((char*)d_ws + bucket_off_b);

    // zero counts, cursor, gcur (contiguous 2N+1 ints)
    k_zero<<<(2 * N + 1 + 255) / 256, 256, 0, stream>>>(wsi, 2 * N + 1);
    k_hist<<<(E + 255) / 256, 256, 0, stream>>>(edge_row, counts, E);
    k_alloc<<<(N + 255) / 256, 256, 0, stream>>>(counts, start, gcur, N);
    k_fill<<<(E + 255) / 256, 256, 0, stream>>>(edge_row, edge_col, edge_val,
                                                start, cursor, bucket, E);
    k_gather<<<(N + 7) / 8, 256, 0, stream>>>(bucket, start, counts, weight,
                                              bias, out, N);
}